// Round 5
// baseline (456.031 us; speedup 1.0000x reference)
//
#include <hip/hip_runtime.h>
#include <math.h>

// Match numpy's non-FMA evaluation of the distance formula (ranking fidelity).
#pragma clang fp contract(off)

#define NPTS 4096
#define KNN  16
#define RPBK 32       // rows per knn group (16 waves x 2 rows/wave)
#define MT   1024     // threads per block (mega + fallback knn)
#define NBLK 256      // mega grid: one block per CU (128 KB LDS forces 1/CU)
#define CAP  128      // filtered-candidate list capacity per row
#define CAPIN 64      // incoming-edge bucket capacity per row
#define SPILLCAP 262144
#define RROWS_C 8     // rows composed per block-iteration in mega row phase

// ordered-uint transform: monotone map f32 -> u32 (canonicalize -0 -> +0 first)
// (used only in rare knn fallback paths; hot paths compare floats directly)
__device__ __forceinline__ unsigned okey(float f) {
    f = f + 0.0f;
    unsigned u = __float_as_uint(f);
    return u ^ (((unsigned)((int)u >> 31)) | 0x80000000u);
}

__device__ __forceinline__ unsigned long long wmin64(unsigned long long v) {
    for (int o = 32; o > 0; o >>= 1) { unsigned long long w = __shfl_xor(v, o); v = w < v ? w : v; }
    return v;
}

// ---------------------------------------------------------------------------
// Software grid barrier (reusable, monotone counter; init kernel zeros it at
// the start of every replay so ticket/target arithmetic stays aligned).
// All 256 blocks are co-resident by construction: 128 KB LDS -> 1 block/CU,
// grid == 256 == CU count. Device-scope RMW + acquire spin per G16.
// ---------------------------------------------------------------------------
__device__ __forceinline__ void gridbar(unsigned* bar) {
    __syncthreads();                        // drains all this block's mem ops
    if (threadIdx.x == 0) {
        unsigned ticket = __hip_atomic_fetch_add(bar, 1u, __ATOMIC_ACQ_REL,
                                                 __HIP_MEMORY_SCOPE_AGENT);
        unsigned target = (ticket / NBLK + 1u) * NBLK;
        while (__hip_atomic_load(bar, __ATOMIC_ACQUIRE,
                                 __HIP_MEMORY_SCOPE_AGENT) < target)
            __builtin_amdgcn_s_sleep(2);
    }
    __syncthreads();
}

// ---------------------------------------------------------------------------
__global__ void init_kernel(float* __restrict__ p, int n) {
    int i = blockIdx.x * blockDim.x + threadIdx.x;
    if (i < n) p[i] = 0.0f;
}

// ---------------------------------------------------------------------------
// T = 16th smallest (by (value, lane)) of the 64 per-lane values.
// Rank via 64 independent broadcasts; ranks are a permutation of 0..63.
// ---------------------------------------------------------------------------
__device__ __forceinline__ float thresh16(float k, int lane) {
    int rank = 0;
    for (int s = 0; s < 64; ++s) {
        float ks = __shfl(k, s);
        rank += (ks < k || (ks == k && s < lane)) ? 1 : 0;
    }
    unsigned long long m = __ballot(rank == 15);
    return __shfl(k, __ffsll(m) - 1);
}

// ---------------------------------------------------------------------------
// Exact top-16 of the candidate list by (d2, idx); winner lands on lane r.
// ---------------------------------------------------------------------------
__device__ __forceinline__ int select16(const float4* __restrict__ spts,
                                        const int* __restrict__ list,
                                        int cnt, float4 P, int lane) {
    if (cnt <= 64) {
        float key = __builtin_huge_valf();
        int m = -1;
        if (lane < cnt) {
            m = list[lane];
            float4 Q = spts[m];
            float dot = (P.x * Q.x + P.y * Q.y) + P.z * Q.z;
            key = (P.w + Q.w) - 2.0f * dot;
        }
        int rank = 0;
        for (int s = 0; s < 64; ++s) {
            float ks = __shfl(key, s);
            rank += (ks < key || (ks == key && s < lane)) ? 1 : 0;
        }
        return __builtin_amdgcn_ds_permute(rank << 2, m);
    }
    if (cnt <= CAP) {
        unsigned long long e0 = ~0ull, e1 = ~0ull;
        if (lane < cnt) {
            int m = list[lane]; float4 Q = spts[m];
            float dot = (P.x * Q.x + P.y * Q.y) + P.z * Q.z;
            float d2  = (P.w + Q.w) - 2.0f * dot;
            e0 = ((unsigned long long)okey(d2) << 32) | (unsigned)m;
        }
        if (lane + 64 < cnt) {
            int m = list[lane + 64]; float4 Q = spts[m];
            float dot = (P.x * Q.x + P.y * Q.y) + P.z * Q.z;
            float d2  = (P.w + Q.w) - 2.0f * dot;
            e1 = ((unsigned long long)okey(d2) << 32) | (unsigned)m;
        }
        int selm = -1;
        unsigned long long c = e0 < e1 ? e0 : e1;
        for (int r = 0; r < KNN; ++r) {
            unsigned long long mn = wmin64(c);
            if (c == mn) {
                if (e0 == mn) e0 = ~0ull; else e1 = ~0ull;
                c = e0 < e1 ? e0 : e1;
            }
            if (lane == r) selm = (int)(unsigned)(mn & 0xFFFFFFFFull);
        }
        return selm;
    }
    unsigned long long last = 0; int selm = -1;
    for (int r = 0; r < KNN; ++r) {
        unsigned long long bestp = ~0ull;
        for (int i = 0; i < NPTS / 64; ++i) {
            int m = i * 64 + lane;
            float4 Q  = spts[m];
            float dot = (P.x * Q.x + P.y * Q.y) + P.z * Q.z;
            float d2  = (P.w + Q.w) - 2.0f * dot;
            unsigned long long key = ((unsigned long long)okey(d2) << 32) | (unsigned)m;
            if (key > last && key < bestp) bestp = key;
        }
        unsigned long long mn = wmin64(bestp);
        if (lane == r) selm = (int)(unsigned)(mn & 0xFFFFFFFFull);
        last = mn;
    }
    return selm;
}

// ---------------------------------------------------------------------------
__device__ __forceinline__ void emit_row(int rowg, int b, int selm, float4 P,
                                         const float4* __restrict__ spts,
                                         float* __restrict__ Dsum,
                                         int* __restrict__ idx_out,
                                         float* __restrict__ w_out,
                                         int* __restrict__ cnt,
                                         int* __restrict__ inc,
                                         int* __restrict__ spillc,
                                         int* __restrict__ spill,
                                         int do_inc, int lane) {
    float wgt = 0.0f;
    if (lane < KNN) {
        int j = selm;
        float4 Q = spts[j];
        float dx = P.x - Q.x, dy = P.y - Q.y, dz = P.z - Q.z;
        float dist2 = (dx * dx + dy * dy) + dz * dz;                // numpy order
        wgt = expf(-(dist2 * 0.5f));                                // == -dist2/2.0
        size_t base = (size_t)rowg * KNN + lane;
        idx_out[base] = j;
        w_out[base]   = wgt;
        int jg = (b << 12) + j;
        atomicAdd(&Dsum[jg], 0.5f * wgt);                           // transpose half
        if (do_inc) {
            int pos = atomicAdd(&cnt[jg], 1);
            if (pos < CAPIN) {
                inc[(size_t)jg * CAPIN + pos] = (int)base;
            } else {
                int sp = atomicAdd(spillc, 1);
                if (sp < SPILLCAP) spill[sp] = (int)base;
            }
        }
    }
    float rs = wgt;
    for (int o = 32; o > 0; o >>= 1) rs += __shfl_xor(rs, o);
    if (lane == 0) atomicAdd(&Dsum[rowg], 0.5f * rs);               // outgoing half
}

// ---------------------------------------------------------------------------
// MEGA: whole pipeline in one persistent dispatch.
//   phase K: knn (threshold-filter + exact select, 2 rows/wave)
//   gridbar -> dis -> gridbar -> row compose/stream -> gridbar -> spill drain
// LDS (128 KB raw, aliased): knn uses spts 64K + lists 16K; row uses 128K.
// ---------------------------------------------------------------------------
__global__ __launch_bounds__(MT, 4) void mega_kernel(
        const float* __restrict__ xyz,
        float* __restrict__ Dsum, float* __restrict__ dis,
        int* __restrict__ idxb, float* __restrict__ wb,
        int* __restrict__ cnt, int* __restrict__ inc,
        int* __restrict__ spillc, int* __restrict__ spill,
        unsigned* __restrict__ bar, int BN, float* __restrict__ L) {
    __shared__ __align__(16) char smem[RROWS_C * NPTS * 4];   // 128 KB
    float4* spts = (float4*)smem;                              // 64 KB
    int (*lists)[CAP] = (int(*)[CAP])(smem + NPTS * 16);       // +16 KB
    float* rowbuf = (float*)smem;                              // 128 KB (row phase)

    const int t    = threadIdx.x;
    const int bk   = blockIdx.x;
    const int lane = t & 63;
    const int wv   = t >> 6;                                   // wave 0..15

    // ================= phase K: knn =================
    const int ngroups = BN / RPBK;
    for (int g = bk; g < ngroups; g += NBLK) {
        const int row0g = g * RPBK;
        const int b     = row0g >> 12;
        const float* X  = xyz + (size_t)b * 3 * NPTS;
        __syncthreads();                         // done with previous spts
        for (int i = t; i < NPTS; i += MT) {
            float x = X[i], y = X[NPTS + i], z = X[2 * NPTS + i];
            spts[i] = make_float4(x, y, z, (x * x + y * y) + z * z);  // numpy order
        }
        __syncthreads();

        const int row0 = row0g + 2 * wv;
        const float4 PA = spts[row0 & (NPTS - 1)];
        const float4 PB = spts[(row0 + 1) & (NPTS - 1)];

        // phase 1: per-lane chunk minima (both rows per point read)
        float bA = __builtin_huge_valf(), bB = __builtin_huge_valf();
        for (int i = 0; i < NPTS / 64; ++i) {
            float4 Q  = spts[i * 64 + lane];
            float dotA = (PA.x * Q.x + PA.y * Q.y) + PA.z * Q.z;   // einsum order
            float d2A  = (PA.w + Q.w) - 2.0f * dotA;               // (sq+sq)-2dot
            float dotB = (PB.x * Q.x + PB.y * Q.y) + PB.z * Q.z;
            float d2B  = (PB.w + Q.w) - 2.0f * dotB;
            bA = fminf(bA, d2A);
            bB = fminf(bB, d2B);
        }
        const float TA = thresh16(bA, lane);     // >= 16th smallest d2, row A
        const float TB = thresh16(bB, lane);

        // phase 2: filter candidates with d2 <= T into LDS lists
        int* listA = &lists[2 * wv][0];
        int* listB = &lists[2 * wv + 1][0];
        int cA = 0, cB = 0;
        for (int i = 0; i < NPTS / 64; ++i) {
            int m = i * 64 + lane;
            float4 Q  = spts[m];
            float dotA = (PA.x * Q.x + PA.y * Q.y) + PA.z * Q.z;
            float d2A  = (PA.w + Q.w) - 2.0f * dotA;
            float dotB = (PB.x * Q.x + PB.y * Q.y) + PB.z * Q.z;
            float d2B  = (PB.w + Q.w) - 2.0f * dotB;
            bool pA = d2A <= TA;
            unsigned long long balA = __ballot(pA);
            if (pA) {
                int pos = cA + __popcll(balA & ((1ull << lane) - 1ull));
                if (pos < CAP) listA[pos] = m;
            }
            cA += (int)__popcll(balA);
            bool pB = d2B <= TB;
            unsigned long long balB = __ballot(pB);
            if (pB) {
                int pos = cB + __popcll(balB & ((1ull << lane) - 1ull));
                if (pos < CAP) listB[pos] = m;
            }
            cB += (int)__popcll(balB);
        }

        // phase 3 + outputs
        int selA = select16(spts, listA, cA, PA, lane);
        int selB = select16(spts, listB, cB, PB, lane);
        emit_row(row0,     b, selA, PA, spts, Dsum, idxb, wb,
                 cnt, inc, spillc, spill, 1, lane);
        emit_row(row0 + 1, b, selB, PB, spts, Dsum, idxb, wb,
                 cnt, inc, spillc, spill, 1, lane);
    }
    gridbar(bar);

    // ================= dis =================
    for (int i = bk * MT + t; i < BN; i += NBLK * MT)
        dis[i] = 1.0f / sqrtf(fmaxf(Dsum[i], 1e-6f));
    gridbar(bar);

    // ================= row compose + stream =================
    // v = -0.5f * w * dis[src] * dis[dst]  (bitwise == verified scatter expr)
    const int rows_per_blk = BN / NBLK;              // 64
    float4* row4 = (float4*)rowbuf;
    for (int it = 0; it < rows_per_blk / RROWS_C; ++it) {
        const int r0 = bk * rows_per_blk + it * RROWS_C;
        const int b0 = r0 >> 12;

        for (int i = t; i < RROWS_C * NPTS / 4; i += MT)
            row4[i] = make_float4(0.0f, 0.0f, 0.0f, 0.0f);
        __syncthreads();

        const int rr = t >> 7;                       // 0..7 (128 thr/row)
        const int tt = t & 127;
        const int r  = r0 + rr;
        float* myrow = rowbuf + rr * NPTS;
        const float dn = dis[r];

        if (tt < KNN) {                              // outgoing (unique cols)
            int g = r * KNN + tt;
            int j = idxb[g];
            float v = -0.5f * wb[g] * dn * dis[(b0 << 12) + j];
            atomicAdd(&myrow[j], v);
        }
        int c = cnt[r];
        if (c > CAPIN) c = CAPIN;                    // overflow -> spill phase
        for (int i = tt; i < c; i += 128) {          // incoming bucket
            int g   = inc[(size_t)r * CAPIN + i];
            int src = g >> 4;
            float v = -0.5f * wb[g] * dis[src] * dn;
            atomicAdd(&myrow[src & (NPTS - 1)], v);
        }
        __syncthreads();

        const int n0 = r0 & (NPTS - 1);
        float4* Lr = (float4*)(L + (size_t)b0 * NPTS * NPTS + (size_t)n0 * NPTS);
        for (int q = t; q < RROWS_C * NPTS / 4; q += MT) {
            float4 v = row4[q];
            int n = n0 + (q >> 10);                  // 1024 float4 per row
            if ((q & 1023) == (n >> 2)) ((float*)&v)[n & 3] += 1.0f;
            Lr[q] = v;
        }
        // store loop reads only this thread's own partition; next iter's
        // zero writes the same partition -> no cross-thread hazard here.
    }
    gridbar(bar);

    // ================= spill drain (practically always empty) =================
    int c = spillc[0];
    if (c > SPILLCAP) c = SPILLCAP;
    for (int i = bk * MT + t; i < c; i += NBLK * MT) {
        int g   = spill[i];
        int src = g >> 4;
        int b   = src >> 12;
        int nn  = src & (NPTS - 1);
        int j   = idxb[g];
        float v = -0.5f * wb[g] * dis[src] * dis[(b << 12) + j];
        atomicAdd(L + (size_t)b * NPTS * NPTS + (size_t)j * NPTS + nn, v);
    }
}

// ---------------------------------------------------------------------------
// Fallback path (verified baseline shape): separate kernels, fill + scatter.
// Used only if the workspace is too small for the fused layout.
// ---------------------------------------------------------------------------
__global__ __launch_bounds__(MT, 4) void knn_kernel(const float* __restrict__ xyz,
                                                    float* __restrict__ Dsum,
                                                    int* __restrict__ idx_out,
                                                    float* __restrict__ w_out) {
    __shared__ float4 spts[NPTS];
    __shared__ int    lists[RPBK][CAP];

    const int t    = threadIdx.x;
    const int lane = t & 63;
    const int wv   = t >> 6;
    const int row0 = blockIdx.x * RPBK + 2 * wv;
    const int b    = row0 >> 12;
    const float* X = xyz + (size_t)b * 3 * NPTS;

    for (int i = t; i < NPTS; i += MT) {
        float x = X[i], y = X[NPTS + i], z = X[2 * NPTS + i];
        spts[i] = make_float4(x, y, z, (x * x + y * y) + z * z);
    }
    __syncthreads();

    const float4 PA = spts[row0 & (NPTS - 1)];
    const float4 PB = spts[(row0 + 1) & (NPTS - 1)];
    float bA = __builtin_huge_valf(), bB = __builtin_huge_valf();
    for (int i = 0; i < NPTS / 64; ++i) {
        float4 Q  = spts[i * 64 + lane];
        float dotA = (PA.x * Q.x + PA.y * Q.y) + PA.z * Q.z;
        float d2A  = (PA.w + Q.w) - 2.0f * dotA;
        float dotB = (PB.x * Q.x + PB.y * Q.y) + PB.z * Q.z;
        float d2B  = (PB.w + Q.w) - 2.0f * dotB;
        bA = fminf(bA, d2A);
        bB = fminf(bB, d2B);
    }
    const float TA = thresh16(bA, lane);
    const float TB = thresh16(bB, lane);
    int* listA = &lists[2 * wv][0];
    int* listB = &lists[2 * wv + 1][0];
    int cA = 0, cB = 0;
    for (int i = 0; i < NPTS / 64; ++i) {
        int m = i * 64 + lane;
        float4 Q  = spts[m];
        float dotA = (PA.x * Q.x + PA.y * Q.y) + PA.z * Q.z;
        float d2A  = (PA.w + Q.w) - 2.0f * dotA;
        float dotB = (PB.x * Q.x + PB.y * Q.y) + PB.z * Q.z;
        float d2B  = (PB.w + Q.w) - 2.0f * dotB;
        bool pA = d2A <= TA;
        unsigned long long balA = __ballot(pA);
        if (pA) {
            int pos = cA + __popcll(balA & ((1ull << lane) - 1ull));
            if (pos < CAP) listA[pos] = m;
        }
        cA += (int)__popcll(balA);
        bool pB = d2B <= TB;
        unsigned long long balB = __ballot(pB);
        if (pB) {
            int pos = cB + __popcll(balB & ((1ull << lane) - 1ull));
            if (pos < CAP) listB[pos] = m;
        }
        cB += (int)__popcll(balB);
    }
    int selA = select16(spts, listA, cA, PA, lane);
    int selB = select16(spts, listB, cB, PB, lane);
    emit_row(row0,     b, selA, PA, spts, Dsum, idx_out, w_out,
             nullptr, nullptr, nullptr, nullptr, 0, lane);
    emit_row(row0 + 1, b, selB, PB, spts, Dsum, idx_out, w_out,
             nullptr, nullptr, nullptr, nullptr, 0, lane);
}

__global__ void dis_kernel(const float* __restrict__ Dsum, float* __restrict__ dis, int n) {
    int i = blockIdx.x * blockDim.x + threadIdx.x;
    if (i < n) dis[i] = 1.0f / sqrtf(fmaxf(Dsum[i], 1e-6f));
}

__global__ __launch_bounds__(256) void fill_kernel(float4* __restrict__ L4, size_t T4) {
    size_t g4     = (size_t)blockIdx.x * blockDim.x + threadIdx.x;
    size_t stride = (size_t)gridDim.x * blockDim.x;
    for (; g4 < T4; g4 += stride) {
        size_t g = g4 << 2;
        int o    = (int)(g & (size_t)(NPTS * (size_t)NPTS - 1));
        int row  = o >> 12;
        int col0 = o & (NPTS - 1);
        float4 v;
        v.x = (row == col0    ) ? 1.0f : 0.0f;
        v.y = (row == col0 + 1) ? 1.0f : 0.0f;
        v.z = (row == col0 + 2) ? 1.0f : 0.0f;
        v.w = (row == col0 + 3) ? 1.0f : 0.0f;
        L4[g4] = v;
    }
}

__global__ __launch_bounds__(256) void scatter_kernel(const int* __restrict__ idxb,
                                                      const float* __restrict__ wb,
                                                      const float* __restrict__ dis,
                                                      float* __restrict__ L) {
    int g   = blockIdx.x * 256 + threadIdx.x;
    int row = g >> 4;
    int b   = row >> 12;
    int n   = row & (NPTS - 1);
    int j   = idxb[g];
    float v = -0.5f * wb[g] * dis[row] * dis[(b << 12) + j];
    float* Lb = L + (size_t)b * NPTS * NPTS;
    atomicAdd(Lb + (size_t)n * NPTS + j, v);
    atomicAdd(Lb + (size_t)j * NPTS + n, v);
}

// ---------------------------------------------------------------------------
extern "C" void kernel_launch(void* const* d_in, const int* in_sizes, int n_in,
                              void* d_out, int out_size, void* d_ws, size_t ws_size,
                              hipStream_t stream) {
    const float* xyz = (const float*)d_in[0];
    const int B  = in_sizes[0] / (3 * NPTS);            // 4
    const int BN = B * NPTS;                            // 16384

    // fused layout (4-byte elems, ~7.5 MB):
    // Dsum[BN] | cnt[BN] | spillc[16] | bar[16] | dis[BN] | idx[BN*K] | w[BN*K]
    //   | inc[BN*CAPIN] | spill[SPILLCAP]
    float*    Dsum   = (float*)d_ws;
    int*      cnt    = (int*)(Dsum + BN);
    int*      spillc = cnt + BN;
    unsigned* bar    = (unsigned*)(spillc + 16);
    float*    dis    = (float*)(bar + 16);
    int*      idxb   = (int*)(dis + BN);
    float*    wb     = (float*)(idxb + (size_t)BN * KNN);
    int*      inc    = (int*)(wb + (size_t)BN * KNN);
    int*      spill  = inc + (size_t)BN * CAPIN;
    float*    L      = (float*)d_out;

    size_t need = ((size_t)BN * (3 + 2 * KNN + CAPIN) + 32 + SPILLCAP) * 4;
    const int fused = (ws_size >= need);

    if (fused) {
        int nz = 2 * BN + 32;                           // Dsum + cnt + spillc + bar
        init_kernel<<<(nz + 255) / 256, 256, 0, stream>>>(Dsum, nz);
        mega_kernel<<<NBLK, MT, 0, stream>>>(xyz, Dsum, dis, idxb, wb,
                                             cnt, inc, spillc, spill,
                                             bar, BN, L);
    } else {
        // fallback: fill + scatter (~2.25 MB workspace)
        float* fDsum = (float*)d_ws;
        float* fdis  = fDsum + BN;
        int*   fidx  = (int*)(fdis + BN);
        float* fwb   = (float*)(fidx + (size_t)BN * KNN);
        init_kernel<<<BN / 256, 256, 0, stream>>>(fDsum, BN);
        knn_kernel<<<BN / RPBK, MT, 0, stream>>>(xyz, fDsum, fidx, fwb);
        dis_kernel<<<BN / 256, 256, 0, stream>>>(fDsum, fdis, BN);
        size_t T4 = (size_t)B * NPTS * NPTS / 4;
        fill_kernel<<<8192, 256, 0, stream>>>((float4*)d_out, T4);
        scatter_kernel<<<(BN * KNN) / 256, 256, 0, stream>>>(fidx, fwb, fdis, L);
    }
}

// Round 6
// 369.868 us; speedup vs baseline: 1.2330x; 1.2330x over previous
//
#include <hip/hip_runtime.h>
#include <math.h>

// Match numpy's non-FMA evaluation of the distance formula (ranking fidelity).
#pragma clang fp contract(off)

#define NPTS 4096
#define KNN  16
#define RW   4          // rows per wave in knn (one Q read feeds 4 rows)
#define KWAVES 4        // waves per knn block
#define KBT  256        // knn block threads
#define KROWS (KWAVES * RW)   // 16 rows per knn block
#define CAP  64         // candidate list capacity (E[cnt]~18; P(>64) ~ 0)
#define CAPIN 64        // incoming-edge bucket capacity per row
#define SPILLCAP 262144
#define RROWS 4         // rows per block in row kernel (64 KB decl + 16 KB rt = 80 KB -> 2/CU)

// ordered-uint transform: monotone map f32 -> u32 (canonicalize -0 -> +0 first)
// (only used in the astronomically-rare full-rescan fallback)
__device__ __forceinline__ unsigned okey(float f) {
    f = f + 0.0f;
    unsigned u = __float_as_uint(f);
    return u ^ (((unsigned)((int)u >> 31)) | 0x80000000u);
}

__device__ __forceinline__ unsigned long long wmin64(unsigned long long v) {
    for (int o = 32; o > 0; o >>= 1) { unsigned long long w = __shfl_xor(v, o); v = w < v ? w : v; }
    return v;
}

// ---------------------------------------------------------------------------
// prep: build pts4[b][n] = (x,y,z,(x^2+y^2)+z^2) (numpy eval order) and zero
// the accumulators (Dsum | cnt | spillc).
// ---------------------------------------------------------------------------
__global__ __launch_bounds__(256) void prep_kernel(const float* __restrict__ xyz,
                                                   float4* __restrict__ pts4,
                                                   float* __restrict__ zbuf,
                                                   int nzero, int BN) {
    int i = blockIdx.x * 256 + threadIdx.x;
    if (i < BN) {
        int b = i >> 12, n = i & (NPTS - 1);
        const float* X = xyz + (size_t)b * 3 * NPTS;
        float x = X[n], y = X[NPTS + n], z = X[2 * NPTS + n];
        pts4[i] = make_float4(x, y, z, (x * x + y * y) + z * z);
    }
    if (i < nzero) zbuf[i] = 0.0f;
}

// ---------------------------------------------------------------------------
// T = 16th smallest (by (value, lane)) of the 64 per-lane values.
// Rank via 64 independent broadcasts; ranks are a permutation of 0..63.
// ---------------------------------------------------------------------------
__device__ __forceinline__ float thresh16(float k, int lane) {
    int rank = 0;
    for (int s = 0; s < 64; ++s) {
        float ks = __shfl(k, s);
        rank += (ks < k || (ks == k && s < lane)) ? 1 : 0;
    }
    unsigned long long m = __ballot(rank == 15);
    return __shfl(k, __ffsll(m) - 1);
}

// ---------------------------------------------------------------------------
// Exact top-16 of the candidate list by (d2, idx); winner lands on lane r.
// Fast path (cnt <= 64): rank + ds_permute (keys unique: list ascending in
// idx => lane order == idx order; inf pads tie-broken by lane).
// Fallback (cnt > 64, astronomically rare): exact 16-round full rescan.
// ---------------------------------------------------------------------------
__device__ __forceinline__ int select16(const float4* __restrict__ pts,
                                        const int* __restrict__ list,
                                        int cnt2, float4 P, int lane) {
    if (cnt2 <= 64) {
        float key = __builtin_huge_valf();
        int m = -1;
        if (lane < cnt2) {
            m = list[lane];
            float4 Q = pts[m];
            float dot = (P.x * Q.x + P.y * Q.y) + P.z * Q.z;
            key = (P.w + Q.w) - 2.0f * dot;
        }
        int rank = 0;
        for (int s = 0; s < 64; ++s) {
            float ks = __shfl(key, s);
            rank += (ks < key || (ks == key && s < lane)) ? 1 : 0;
        }
        return __builtin_amdgcn_ds_permute(rank << 2, m);
    }
    // full-rescan fallback: exact 16 rounds of strictly-increasing wave-min
    unsigned long long last = 0; int selm = -1;
    for (int r = 0; r < KNN; ++r) {
        unsigned long long bestp = ~0ull;
        for (int i = 0; i < NPTS / 64; ++i) {
            int m = i * 64 + lane;
            float4 Q  = pts[m];
            float dot = (P.x * Q.x + P.y * Q.y) + P.z * Q.z;
            float d2  = (P.w + Q.w) - 2.0f * dot;
            unsigned long long key = ((unsigned long long)okey(d2) << 32) | (unsigned)m;
            if (key > last && key < bestp) bestp = key;
        }
        unsigned long long mn = wmin64(bestp);
        if (lane == r) selm = (int)(unsigned)(mn & 0xFFFFFFFFull);
        last = mn;
    }
    return selm;
}

// ---------------------------------------------------------------------------
// Winners on lanes 0..15: exact-diff weights, outputs, degree atomics, and
// (fused path) append to the target row's incoming bucket.
// ---------------------------------------------------------------------------
__device__ __forceinline__ void emit_row(int rowg, int b, int selm, float4 P,
                                         const float4* __restrict__ pts,
                                         float* __restrict__ Dsum,
                                         int* __restrict__ idx_out,
                                         float* __restrict__ w_out,
                                         int* __restrict__ cnt,
                                         int* __restrict__ inc,
                                         int* __restrict__ spillc,
                                         int* __restrict__ spill,
                                         int do_inc, int lane) {
    float wgt = 0.0f;
    if (lane < KNN) {
        int j = selm;
        float4 Q = pts[j];
        float dx = P.x - Q.x, dy = P.y - Q.y, dz = P.z - Q.z;
        float dist2 = (dx * dx + dy * dy) + dz * dz;                // numpy order
        wgt = expf(-(dist2 * 0.5f));                                // == -dist2/2.0
        size_t base = (size_t)rowg * KNN + lane;
        idx_out[base] = j;
        w_out[base]   = wgt;
        int jg = (b << 12) + j;
        atomicAdd(&Dsum[jg], 0.5f * wgt);                           // transpose half
        if (do_inc) {
            int pos = atomicAdd(&cnt[jg], 1);
            if (pos < CAPIN) {
                inc[(size_t)jg * CAPIN + pos] = (int)base;
            } else {
                int sp = atomicAdd(spillc, 1);
                if (sp < SPILLCAP) spill[sp] = (int)base;
            }
        }
    }
    float rs = wgt;
    for (int o = 32; o > 0; o >>= 1) rs += __shfl_xor(rs, o);
    if (lane == 0) atomicAdd(&Dsum[rowg], 0.5f * rs);               // outgoing half
}

// ---------------------------------------------------------------------------
// KNN: threshold-filter + exact small select, 4 rows/wave, candidates
// streamed from L2 (pts4 is 256 KB/batch, L2-resident) with coalesced
// float4 loads. No spts LDS, no barriers; LDS = 4 KB of candidate lists
// -> occupancy is VGPR-bound (~6 waves/SIMD), not LDS-bound.
// Selection order is (d2, idx) lexicographic == lax.top_k order.
// ---------------------------------------------------------------------------
__global__ __launch_bounds__(KBT, 4) void knn_kernel(const float4* __restrict__ pts4,
                                                     float* __restrict__ Dsum,
                                                     int* __restrict__ idx_out,
                                                     float* __restrict__ w_out,
                                                     int* __restrict__ cnt,
                                                     int* __restrict__ inc,
                                                     int* __restrict__ spillc,
                                                     int* __restrict__ spill,
                                                     int do_inc) {
    __shared__ int lists[KROWS][CAP];        // 4 KB

    const int t    = threadIdx.x;
    const int lane = t & 63;
    const int wv   = t >> 6;                              // wave 0..3
    const int row0 = blockIdx.x * KROWS + wv * RW;        // 4 consecutive rows
    const int b    = row0 >> 12;
    const float4* P4 = pts4 + ((size_t)b << 12);

    float4 P[RW]; float bm[RW];
#pragma unroll
    for (int r = 0; r < RW; ++r) {
        P[r]  = P4[(row0 + r) & (NPTS - 1)];
        bm[r] = __builtin_huge_valf();
    }

    // ---- phase 1: per-lane chunk minima (one Q read feeds 4 rows) ----
#pragma unroll 4
    for (int i = 0; i < NPTS / 64; ++i) {
        float4 Q = P4[i * 64 + lane];
#pragma unroll
        for (int r = 0; r < RW; ++r) {
            float dot = (P[r].x * Q.x + P[r].y * Q.y) + P[r].z * Q.z;  // einsum order
            float d2  = (P[r].w + Q.w) - 2.0f * dot;                   // (sq+sq)-2dot
            bm[r] = fminf(bm[r], d2);
        }
    }
    float T[RW]; int cc[RW];
#pragma unroll
    for (int r = 0; r < RW; ++r) { T[r] = thresh16(bm[r], lane); cc[r] = 0; }

    // ---- phase 2: filter candidates with d2 <= T into LDS lists ----
#pragma unroll 2
    for (int i = 0; i < NPTS / 64; ++i) {
        int m = i * 64 + lane;
        float4 Q = P4[m];
#pragma unroll
        for (int r = 0; r < RW; ++r) {
            float dot = (P[r].x * Q.x + P[r].y * Q.y) + P[r].z * Q.z;
            float d2  = (P[r].w + Q.w) - 2.0f * dot;
            bool pass = d2 <= T[r];
            unsigned long long bal = __ballot(pass);
            if (pass) {
                int pos = cc[r] + __popcll(bal & ((1ull << lane) - 1ull));
                if (pos < CAP) lists[wv * RW + r][pos] = m;
            }
            cc[r] += (int)__popcll(bal);
        }
    }

    // ---- phase 3 + outputs ----
#pragma unroll
    for (int r = 0; r < RW; ++r) {
        int sel = select16(P4, &lists[wv * RW + r][0], cc[r], P[r], lane);
        emit_row(row0 + r, b, sel, P[r], P4, Dsum, idx_out, w_out,
                 cnt, inc, spillc, spill, do_inc, lane);
    }
}

// ---------------------------------------------------------------------------
__global__ void dis_kernel(const float* __restrict__ Dsum, float* __restrict__ dis, int n) {
    int i = blockIdx.x * blockDim.x + threadIdx.x;
    if (i < n) dis[i] = 1.0f / sqrtf(fmaxf(Dsum[i], 1e-6f));
}

// ---------------------------------------------------------------------------
// Fused fill+scatter: one 1024-thread block composes RROWS=4 consecutive
// output rows in LDS (64 KB decl; +16 KB runtime = 80 KB -> 2 blocks/CU)
// and streams them out once with coalesced float4 stores.
// Value expression matches scatter_kernel bitwise:
//   v = -0.5f * w * dis[src] * dis[dst]   (left-to-right evaluation)
// ---------------------------------------------------------------------------
__global__ __launch_bounds__(1024, 4) void row_kernel(const int* __restrict__ idxb,
                                                      const float* __restrict__ wb,
                                                      const float* __restrict__ dis,
                                                      const int* __restrict__ cnt,
                                                      const int* __restrict__ inc,
                                                      float* __restrict__ L) {
    __shared__ float row[RROWS * NPTS];          // 64 KB
    const int r0 = blockIdx.x * RROWS;           // first global row
    const int b  = r0 >> 12;

    float4* row4 = (float4*)row;
    for (int i = threadIdx.x; i < RROWS * NPTS / 4; i += 1024)
        row4[i] = make_float4(0.0f, 0.0f, 0.0f, 0.0f);
    __syncthreads();

    // sparse phase: 256 threads per row
    const int rr = threadIdx.x >> 8;             // 0..RROWS-1
    const int tt = threadIdx.x & 255;
    const int r  = r0 + rr;
    float* myrow = row + rr * NPTS;
    const float dn = dis[r];

    if (tt < KNN) {                              // outgoing (unique cols)
        int g = r * KNN + tt;
        int j = idxb[g];
        float v = -0.5f * wb[g] * dn * dis[(b << 12) + j];
        atomicAdd(&myrow[j], v);
    }
    int c = cnt[r];
    if (c > CAPIN) c = CAPIN;                    // overflow -> spill_kernel
    for (int i = tt; i < c; i += 256) {          // incoming bucket
        int g   = inc[(size_t)r * CAPIN + i];
        int src = g >> 4;
        float v = -0.5f * wb[g] * dis[src] * dn;
        atomicAdd(&myrow[src & (NPTS - 1)], v);
    }
    __syncthreads();

    // stream out (rows consecutive in memory), merging the unit diagonal
    const int n0 = r0 & (NPTS - 1);
    float4* Lr = (float4*)(L + (size_t)b * NPTS * NPTS + (size_t)n0 * NPTS);
    for (int q = threadIdx.x; q < RROWS * NPTS / 4; q += 1024) {
        float4 v = row4[q];
        int n = n0 + (q >> 10);                  // 1024 float4 per row
        if ((q & 1023) == (n >> 2)) ((float*)&v)[n & 3] += 1.0f;
        Lr[q] = v;
    }
}

// ---------------------------------------------------------------------------
// Drain the (practically always empty) incoming-bucket overflow list.
// ---------------------------------------------------------------------------
__global__ __launch_bounds__(256) void spill_kernel(const int* __restrict__ spillc,
                                                    const int* __restrict__ spill,
                                                    const int* __restrict__ idxb,
                                                    const float* __restrict__ wb,
                                                    const float* __restrict__ dis,
                                                    float* __restrict__ L) {
    int c = spillc[0];
    if (c > SPILLCAP) c = SPILLCAP;
    for (int i = blockIdx.x * blockDim.x + threadIdx.x; i < c;
         i += gridDim.x * blockDim.x) {
        int g   = spill[i];
        int src = g >> 4;
        int b   = src >> 12;
        int nn  = src & (NPTS - 1);
        int j   = idxb[g];
        float v = -0.5f * wb[g] * dis[src] * dis[(b << 12) + j];
        atomicAdd(L + (size_t)b * NPTS * NPTS + (size_t)j * NPTS + nn, v);
    }
}

// ---------------------------------------------------------------------------
// Fallback path (small workspace): dense fill + global-atomic scatter.
// ---------------------------------------------------------------------------
__global__ __launch_bounds__(256) void fill_kernel(float4* __restrict__ L4, size_t T4) {
    size_t g4     = (size_t)blockIdx.x * blockDim.x + threadIdx.x;
    size_t stride = (size_t)gridDim.x * blockDim.x;
    for (; g4 < T4; g4 += stride) {
        size_t g = g4 << 2;
        int o    = (int)(g & (size_t)(NPTS * (size_t)NPTS - 1));
        int row  = o >> 12;
        int col0 = o & (NPTS - 1);
        float4 v;
        v.x = (row == col0    ) ? 1.0f : 0.0f;
        v.y = (row == col0 + 1) ? 1.0f : 0.0f;
        v.z = (row == col0 + 2) ? 1.0f : 0.0f;
        v.w = (row == col0 + 3) ? 1.0f : 0.0f;
        L4[g4] = v;
    }
}

__global__ __launch_bounds__(256) void scatter_kernel(const int* __restrict__ idxb,
                                                      const float* __restrict__ wb,
                                                      const float* __restrict__ dis,
                                                      float* __restrict__ L) {
    int g   = blockIdx.x * 256 + threadIdx.x;
    int row = g >> 4;
    int b   = row >> 12;
    int n   = row & (NPTS - 1);
    int j   = idxb[g];
    float v = -0.5f * wb[g] * dis[row] * dis[(b << 12) + j];
    float* Lb = L + (size_t)b * NPTS * NPTS;
    atomicAdd(Lb + (size_t)n * NPTS + j, v);
    atomicAdd(Lb + (size_t)j * NPTS + n, v);
}

// ---------------------------------------------------------------------------
extern "C" void kernel_launch(void* const* d_in, const int* in_sizes, int n_in,
                              void* d_out, int out_size, void* d_ws, size_t ws_size,
                              hipStream_t stream) {
    const float* xyz = (const float*)d_in[0];
    const int B  = in_sizes[0] / (3 * NPTS);            // 4
    const int BN = B * NPTS;                            // 16384

    // fused layout (4-byte elems, ~7.8 MB):
    // pts4[BN]x4 | Dsum[BN] | cnt[BN] | spillc[16] | dis[BN] | idx[BN*K]
    //   | w[BN*K] | inc[BN*CAPIN] | spill[SPILLCAP]
    float4* pts4   = (float4*)d_ws;
    float*  Dsum   = (float*)(pts4 + BN);
    int*    cnt    = (int*)(Dsum + BN);
    int*    spillc = cnt + BN;
    float*  dis    = (float*)(spillc + 16);
    int*    idxb   = (int*)(dis + BN);
    float*  wb     = (float*)(idxb + (size_t)BN * KNN);
    int*    inc    = (int*)(wb + (size_t)BN * KNN);
    int*    spill  = inc + (size_t)BN * CAPIN;
    float*  L      = (float*)d_out;

    size_t need = ((size_t)BN * (4 + 3 + 2 * KNN + CAPIN) + 16 + SPILLCAP) * 4;
    const int fused = (ws_size >= need);

    if (fused) {
        int nz = 2 * BN + 16;                           // Dsum + cnt + spillc
        int mx = nz > BN ? nz : BN;
        prep_kernel<<<(mx + 255) / 256, 256, 0, stream>>>(xyz, pts4, Dsum, nz, BN);
        knn_kernel<<<BN / KROWS, KBT, 0, stream>>>(pts4, Dsum, idxb, wb,
                                                   cnt, inc, spillc, spill, 1);
        dis_kernel<<<BN / 256, 256, 0, stream>>>(Dsum, dis, BN);
        row_kernel<<<BN / RROWS, 1024, 0, stream>>>(idxb, wb, dis, cnt, inc, L);
        spill_kernel<<<64, 256, 0, stream>>>(spillc, spill, idxb, wb, dis, L);
    } else {
        // fallback: fill + scatter (~2.6 MB workspace)
        float4* fpts  = (float4*)d_ws;
        float*  fDsum = (float*)(fpts + BN);
        float*  fdis  = fDsum + BN;
        int*    fidx  = (int*)(fdis + BN);
        float*  fwb   = (float*)(fidx + (size_t)BN * KNN);
        prep_kernel<<<(BN + 255) / 256, 256, 0, stream>>>(xyz, fpts, fDsum, BN, BN);
        knn_kernel<<<BN / KROWS, KBT, 0, stream>>>(fpts, fDsum, fidx, fwb,
                                                   nullptr, nullptr, nullptr, nullptr, 0);
        dis_kernel<<<BN / 256, 256, 0, stream>>>(fDsum, fdis, BN);
        size_t T4 = (size_t)B * NPTS * NPTS / 4;
        fill_kernel<<<8192, 256, 0, stream>>>((float4*)d_out, T4);
        scatter_kernel<<<(BN * KNN) / 256, 256, 0, stream>>>(fidx, fwb, fdis, L);
    }
}

// Round 7
// 358.173 us; speedup vs baseline: 1.2732x; 1.0327x over previous
//
#include <hip/hip_runtime.h>
#include <math.h>

// Match numpy's non-FMA evaluation of the distance formula (ranking fidelity).
#pragma clang fp contract(off)

#define NPTS 4096
#define KNN  16
#define RPBK 32       // rows per block in knn kernel (16 waves x 2 rows/wave)
#define KT   1024     // knn threads per block
#define CAP  128      // filtered-candidate list capacity per row (knn phase 2)
#define CAPIN 64      // incoming-edge bucket capacity per row
#define SPILLCAP 262144
#define RROWS 4       // rows per block in row kernel (64 KB decl + 16 KB rt = 80 KB -> 2/CU)

// ordered-uint transform: monotone map f32 -> u32 (canonicalize -0 -> +0 first)
// (used only in rare knn fallback paths; hot paths compare floats directly)
__device__ __forceinline__ unsigned okey(float f) {
    f = f + 0.0f;
    unsigned u = __float_as_uint(f);
    return u ^ (((unsigned)((int)u >> 31)) | 0x80000000u);
}

__device__ __forceinline__ unsigned long long wmin64(unsigned long long v) {
    for (int o = 32; o > 0; o >>= 1) { unsigned long long w = __shfl_xor(v, o); v = w < v ? w : v; }
    return v;
}

// dis recompute (bitwise == old dis_kernel expression)
__device__ __forceinline__ float disv(const float* __restrict__ Dsum, int i) {
    return 1.0f / sqrtf(fmaxf(Dsum[i], 1e-6f));
}

// ---------------------------------------------------------------------------
__global__ void zero_kernel(float* __restrict__ p, int n) {
    int i = blockIdx.x * blockDim.x + threadIdx.x;
    if (i < n) p[i] = 0.0f;
}

// ---------------------------------------------------------------------------
// T = 16th smallest (by (value, lane)) of the 64 per-lane values.
// Rank via 64 independent broadcasts; ranks are a permutation of 0..63.
// ---------------------------------------------------------------------------
__device__ __forceinline__ float thresh16(float k, int lane) {
    int rank = 0;
    for (int s = 0; s < 64; ++s) {
        float ks = __shfl(k, s);
        rank += (ks < k || (ks == k && s < lane)) ? 1 : 0;
    }
    unsigned long long m = __ballot(rank == 15);
    return __shfl(k, __ffsll(m) - 1);
}

// ---------------------------------------------------------------------------
// Exact top-16 of the candidate list by (d2, idx); winner lands on lane r.
// Fast path (cnt <= 64): rank + ds_permute. Mid path (cnt <= CAP): 16-round
// u64 extraction. Slow path (cnt > CAP, astronomically rare): full rescan.
// ---------------------------------------------------------------------------
__device__ __forceinline__ int select16(const float4* __restrict__ spts,
                                        const int* __restrict__ list,
                                        int cnt2, float4 P, int lane) {
    if (cnt2 <= 64) {
        float key = __builtin_huge_valf();
        int m = -1;
        if (lane < cnt2) {
            m = list[lane];
            float4 Q = spts[m];
            float dot = (P.x * Q.x + P.y * Q.y) + P.z * Q.z;
            key = (P.w + Q.w) - 2.0f * dot;
        }
        int rank = 0;
        for (int s = 0; s < 64; ++s) {
            float ks = __shfl(key, s);
            rank += (ks < key || (ks == key && s < lane)) ? 1 : 0;
        }
        return __builtin_amdgcn_ds_permute(rank << 2, m);
    }
    if (cnt2 <= CAP) {
        unsigned long long e0 = ~0ull, e1 = ~0ull;
        if (lane < cnt2) {
            int m = list[lane]; float4 Q = spts[m];
            float dot = (P.x * Q.x + P.y * Q.y) + P.z * Q.z;
            float d2  = (P.w + Q.w) - 2.0f * dot;
            e0 = ((unsigned long long)okey(d2) << 32) | (unsigned)m;
        }
        if (lane + 64 < cnt2) {
            int m = list[lane + 64]; float4 Q = spts[m];
            float dot = (P.x * Q.x + P.y * Q.y) + P.z * Q.z;
            float d2  = (P.w + Q.w) - 2.0f * dot;
            e1 = ((unsigned long long)okey(d2) << 32) | (unsigned)m;
        }
        int selm = -1;
        unsigned long long c = e0 < e1 ? e0 : e1;
        for (int r = 0; r < KNN; ++r) {
            unsigned long long mn = wmin64(c);
            if (c == mn) {
                if (e0 == mn) e0 = ~0ull; else e1 = ~0ull;
                c = e0 < e1 ? e0 : e1;
            }
            if (lane == r) selm = (int)(unsigned)(mn & 0xFFFFFFFFull);
        }
        return selm;
    }
    unsigned long long last = 0; int selm = -1;
    for (int r = 0; r < KNN; ++r) {
        unsigned long long bestp = ~0ull;
        for (int i = 0; i < NPTS / 64; ++i) {
            int m = i * 64 + lane;
            float4 Q  = spts[m];
            float dot = (P.x * Q.x + P.y * Q.y) + P.z * Q.z;
            float d2  = (P.w + Q.w) - 2.0f * dot;
            unsigned long long key = ((unsigned long long)okey(d2) << 32) | (unsigned)m;
            if (key > last && key < bestp) bestp = key;
        }
        unsigned long long mn = wmin64(bestp);
        if (lane == r) selm = (int)(unsigned)(mn & 0xFFFFFFFFull);
        last = mn;
    }
    return selm;
}

// ---------------------------------------------------------------------------
// Winners on lanes 0..15: exact-diff weights, outputs, degree atomics, and
// (fused path) append to the target row's incoming bucket.
// ---------------------------------------------------------------------------
__device__ __forceinline__ void emit_row(int rowg, int b, int selm, float4 P,
                                         const float4* __restrict__ spts,
                                         float* __restrict__ Dsum,
                                         int* __restrict__ idx_out,
                                         float* __restrict__ w_out,
                                         int* __restrict__ cnt,
                                         int* __restrict__ inc,
                                         int* __restrict__ spillc,
                                         int* __restrict__ spill,
                                         int do_inc, int lane) {
    float wgt = 0.0f;
    if (lane < KNN) {
        int j = selm;
        float4 Q = spts[j];
        float dx = P.x - Q.x, dy = P.y - Q.y, dz = P.z - Q.z;
        float dist2 = (dx * dx + dy * dy) + dz * dz;                // numpy order
        wgt = expf(-(dist2 * 0.5f));                                // == -dist2/2.0
        size_t base = (size_t)rowg * KNN + lane;
        idx_out[base] = j;
        w_out[base]   = wgt;
        int jg = (b << 12) + j;
        atomicAdd(&Dsum[jg], 0.5f * wgt);                           // transpose half
        if (do_inc) {
            int pos = atomicAdd(&cnt[jg], 1);
            if (pos < CAPIN) {
                inc[(size_t)jg * CAPIN + pos] = (int)base;
            } else {
                int sp = atomicAdd(spillc, 1);
                if (sp < SPILLCAP) spill[sp] = (int)base;
            }
        }
    }
    float rs = wgt;
    for (int o = 32; o > 0; o >>= 1) rs += __shfl_xor(rs, o);
    if (lane == 0) atomicAdd(&Dsum[rowg], 0.5f * rs);               // outgoing half
}

// ---------------------------------------------------------------------------
// KNN (R4-proven): LDS-staged points, threshold-filter + exact small select,
// TWO rows per wave. Selection order (d2, idx) == lax.top_k order.
// launch_bounds min-waves/EU = 4: 8 would cap VGPRs at 64 and spill.
// ---------------------------------------------------------------------------
__global__ __launch_bounds__(KT, 4) void knn_kernel(const float* __restrict__ xyz,
                                                    float* __restrict__ Dsum,
                                                    int* __restrict__ idx_out,
                                                    float* __restrict__ w_out,
                                                    int* __restrict__ cnt,
                                                    int* __restrict__ inc,
                                                    int* __restrict__ spillc,
                                                    int* __restrict__ spill,
                                                    int do_inc) {
    __shared__ float4 spts[NPTS];            // 64 KB: (x,y,z,|p|^2)
    __shared__ int    lists[RPBK][CAP];      // 16 KB

    const int t    = threadIdx.x;
    const int lane = t & 63;
    const int wv   = t >> 6;                              // wave id 0..15
    const int row0 = blockIdx.x * RPBK + 2 * wv;          // this wave: row0, row0+1
    const int b    = row0 >> 12;
    const float* X = xyz + (size_t)b * 3 * NPTS;

    for (int i = t; i < NPTS; i += KT) {
        float x = X[i], y = X[NPTS + i], z = X[2 * NPTS + i];
        spts[i] = make_float4(x, y, z, (x * x + y * y) + z * z);   // numpy order
    }
    __syncthreads();

    const float4 PA = spts[row0 & (NPTS - 1)];
    const float4 PB = spts[(row0 + 1) & (NPTS - 1)];

    // ---- phase 1: per-lane chunk minima (both rows per point read) ----
    float bA = __builtin_huge_valf(), bB = __builtin_huge_valf();
    for (int i = 0; i < NPTS / 64; ++i) {
        float4 Q  = spts[i * 64 + lane];
        float dotA = (PA.x * Q.x + PA.y * Q.y) + PA.z * Q.z;       // einsum order
        float d2A  = (PA.w + Q.w) - 2.0f * dotA;                   // (sq+sq)-2dot
        float dotB = (PB.x * Q.x + PB.y * Q.y) + PB.z * Q.z;
        float d2B  = (PB.w + Q.w) - 2.0f * dotB;
        bA = fminf(bA, d2A);
        bB = fminf(bB, d2B);
    }
    const float TA = thresh16(bA, lane);     // >= 16th smallest d2, row A
    const float TB = thresh16(bB, lane);

    // ---- phase 2: filter candidates with d2 <= T into LDS lists ----
    int* listA = &lists[2 * wv][0];
    int* listB = &lists[2 * wv + 1][0];
    int cA = 0, cB = 0;
    for (int i = 0; i < NPTS / 64; ++i) {
        int m = i * 64 + lane;
        float4 Q  = spts[m];
        float dotA = (PA.x * Q.x + PA.y * Q.y) + PA.z * Q.z;
        float d2A  = (PA.w + Q.w) - 2.0f * dotA;
        float dotB = (PB.x * Q.x + PB.y * Q.y) + PB.z * Q.z;
        float d2B  = (PB.w + Q.w) - 2.0f * dotB;
        bool pA = d2A <= TA;
        unsigned long long balA = __ballot(pA);
        if (pA) {
            int pos = cA + __popcll(balA & ((1ull << lane) - 1ull));
            if (pos < CAP) listA[pos] = m;
        }
        cA += (int)__popcll(balA);
        bool pB = d2B <= TB;
        unsigned long long balB = __ballot(pB);
        if (pB) {
            int pos = cB + __popcll(balB & ((1ull << lane) - 1ull));
            if (pos < CAP) listB[pos] = m;
        }
        cB += (int)__popcll(balB);
    }

    // ---- phase 3 + outputs, per row ----
    int selA = select16(spts, listA, cA, PA, lane);
    int selB = select16(spts, listB, cB, PB, lane);
    emit_row(row0,     b, selA, PA, spts, Dsum, idx_out, w_out,
             cnt, inc, spillc, spill, do_inc, lane);
    emit_row(row0 + 1, b, selB, PB, spts, Dsum, idx_out, w_out,
             cnt, inc, spillc, spill, do_inc, lane);
}

// ---------------------------------------------------------------------------
// Fused fill+scatter+dis+spill: one 1024-thread block composes RROWS=4
// consecutive output rows in LDS and streams them out once. dis values are
// recomputed inline from Dsum (bitwise == old dis_kernel expression); the
// (always-empty) spill list is drained per-block before streaming.
// Value expression matches verified scatter bitwise:
//   v = -0.5f * w * dis[src] * dis[dst]   (left-to-right evaluation)
// ---------------------------------------------------------------------------
__global__ __launch_bounds__(1024, 4) void row_kernel(const int* __restrict__ idxb,
                                                      const float* __restrict__ wb,
                                                      const float* __restrict__ Dsum,
                                                      const int* __restrict__ cnt,
                                                      const int* __restrict__ inc,
                                                      const int* __restrict__ spillc,
                                                      const int* __restrict__ spill,
                                                      float* __restrict__ L) {
    __shared__ float row[RROWS * NPTS];          // 64 KB
    const int r0 = blockIdx.x * RROWS;           // first global row
    const int b  = r0 >> 12;

    float4* row4 = (float4*)row;
    for (int i = threadIdx.x; i < RROWS * NPTS / 4; i += 1024)
        row4[i] = make_float4(0.0f, 0.0f, 0.0f, 0.0f);
    __syncthreads();

    // sparse phase: 256 threads per row
    const int rr = threadIdx.x >> 8;             // 0..RROWS-1
    const int tt = threadIdx.x & 255;
    const int r  = r0 + rr;
    float* myrow = row + rr * NPTS;
    const float dn = disv(Dsum, r);

    if (tt < KNN) {                              // outgoing (unique cols)
        int g = r * KNN + tt;
        int j = idxb[g];
        float v = -0.5f * wb[g] * dn * disv(Dsum, (b << 12) + j);
        atomicAdd(&myrow[j], v);
    }
    int c = cnt[r];
    if (c > CAPIN) c = CAPIN;                    // overflow -> spill drain below
    for (int i = tt; i < c; i += 256) {          // incoming bucket
        int g   = inc[(size_t)r * CAPIN + i];
        int src = g >> 4;
        float v = -0.5f * wb[g] * disv(Dsum, src) * dn;
        atomicAdd(&myrow[src & (NPTS - 1)], v);
    }

    // spill drain for THIS block's rows (practically always empty: one
    // scalar load + branch). Entries: source edge g whose target row
    // (b<<12)+idxb[g] overflowed its bucket.
    int sc = spillc[0];
    if (sc > 0) {
        if (sc > SPILLCAP) sc = SPILLCAP;
        for (int i = threadIdx.x; i < sc; i += 1024) {
            int g   = spill[i];
            int src = g >> 4;
            int jg  = ((src >> 12) << 12) + idxb[g];     // target row global
            if (jg >= r0 && jg < r0 + RROWS) {
                float v = -0.5f * wb[g] * disv(Dsum, src) * disv(Dsum, jg);
                atomicAdd(&row[(jg - r0) * NPTS + (src & (NPTS - 1))], v);
            }
        }
    }
    __syncthreads();

    // stream out (rows consecutive in memory), merging the unit diagonal
    const int n0 = r0 & (NPTS - 1);
    float4* Lr = (float4*)(L + (size_t)b * NPTS * NPTS + (size_t)n0 * NPTS);
    for (int q = threadIdx.x; q < RROWS * NPTS / 4; q += 1024) {
        float4 v = row4[q];
        int n = n0 + (q >> 10);                  // 1024 float4 per row
        if ((q & 1023) == (n >> 2)) ((float*)&v)[n & 3] += 1.0f;
        Lr[q] = v;
    }
}

// ---------------------------------------------------------------------------
// Fallback path (small workspace): dense fill + global-atomic scatter.
// ---------------------------------------------------------------------------
__global__ void dis_kernel(const float* __restrict__ Dsum, float* __restrict__ dis, int n) {
    int i = blockIdx.x * blockDim.x + threadIdx.x;
    if (i < n) dis[i] = 1.0f / sqrtf(fmaxf(Dsum[i], 1e-6f));
}

__global__ __launch_bounds__(256) void fill_kernel(float4* __restrict__ L4, size_t T4) {
    size_t g4     = (size_t)blockIdx.x * blockDim.x + threadIdx.x;
    size_t stride = (size_t)gridDim.x * blockDim.x;
    for (; g4 < T4; g4 += stride) {
        size_t g = g4 << 2;
        int o    = (int)(g & (size_t)(NPTS * (size_t)NPTS - 1));
        int row  = o >> 12;
        int col0 = o & (NPTS - 1);
        float4 v;
        v.x = (row == col0    ) ? 1.0f : 0.0f;
        v.y = (row == col0 + 1) ? 1.0f : 0.0f;
        v.z = (row == col0 + 2) ? 1.0f : 0.0f;
        v.w = (row == col0 + 3) ? 1.0f : 0.0f;
        L4[g4] = v;
    }
}

__global__ __launch_bounds__(256) void scatter_kernel(const int* __restrict__ idxb,
                                                      const float* __restrict__ wb,
                                                      const float* __restrict__ dis,
                                                      float* __restrict__ L) {
    int g   = blockIdx.x * 256 + threadIdx.x;
    int row = g >> 4;
    int b   = row >> 12;
    int n   = row & (NPTS - 1);
    int j   = idxb[g];
    float v = -0.5f * wb[g] * dis[row] * dis[(b << 12) + j];
    float* Lb = L + (size_t)b * NPTS * NPTS;
    atomicAdd(Lb + (size_t)n * NPTS + j, v);
    atomicAdd(Lb + (size_t)j * NPTS + n, v);
}

// ---------------------------------------------------------------------------
extern "C" void kernel_launch(void* const* d_in, const int* in_sizes, int n_in,
                              void* d_out, int out_size, void* d_ws, size_t ws_size,
                              hipStream_t stream) {
    const float* xyz = (const float*)d_in[0];
    const int B  = in_sizes[0] / (3 * NPTS);            // 4
    const int BN = B * NPTS;                            // 16384

    // fused layout (4-byte elems, ~7.4 MB):
    // Dsum[BN] | cnt[BN] | spillc[16] | idx[BN*K] | w[BN*K]
    //   | inc[BN*CAPIN] | spill[SPILLCAP]
    float* Dsum   = (float*)d_ws;
    int*   cnt    = (int*)(Dsum + BN);
    int*   spillc = cnt + BN;
    int*   idxb   = (int*)(spillc + 16);
    float* wb     = (float*)(idxb + (size_t)BN * KNN);
    int*   inc    = (int*)(wb + (size_t)BN * KNN);
    int*   spill  = inc + (size_t)BN * CAPIN;
    float* L      = (float*)d_out;

    size_t need = ((size_t)BN * (2 + 2 * KNN + CAPIN) + 16 + SPILLCAP) * 4;
    const int fused = (ws_size >= need);

    if (fused) {
        int nz = 2 * BN + 16;                           // Dsum + cnt + spillc
        zero_kernel<<<(nz + 255) / 256, 256, 0, stream>>>(Dsum, nz);
        knn_kernel<<<BN / RPBK, KT, 0, stream>>>(xyz, Dsum, idxb, wb,
                                                 cnt, inc, spillc, spill, 1);
        row_kernel<<<BN / RROWS, 1024, 0, stream>>>(idxb, wb, Dsum,
                                                    cnt, inc, spillc, spill, L);
    } else {
        // fallback: fill + scatter (~2.25 MB workspace)
        float* fDsum = (float*)d_ws;
        float* fdis  = fDsum + BN;
        int*   fidx  = (int*)(fdis + BN);
        float* fwb   = (float*)(fidx + (size_t)BN * KNN);
        zero_kernel<<<BN / 256, 256, 0, stream>>>(fDsum, BN);
        knn_kernel<<<BN / RPBK, KT, 0, stream>>>(xyz, fDsum, fidx, fwb,
                                                 nullptr, nullptr, nullptr, nullptr, 0);
        dis_kernel<<<BN / 256, 256, 0, stream>>>(fDsum, fdis, BN);
        size_t T4 = (size_t)B * NPTS * NPTS / 4;
        fill_kernel<<<8192, 256, 0, stream>>>((float4*)d_out, T4);
        scatter_kernel<<<(BN * KNN) / 256, 256, 0, stream>>>(fidx, fwb, fdis, L);
    }
}